// Round 12
// baseline (6854.095 us; speedup 1.0000x reference)
//
#include <hip/hip_runtime.h>

#define B_ 512
#define L_ 1000
#define H_ 128

typedef _Float16 v8h __attribute__((ext_vector_type(8)));
typedef _Float16 h2t __attribute__((ext_vector_type(2)));
typedef float v4f __attribute__((ext_vector_type(4)));

__device__ __forceinline__ float sigmoid_f(float x) {
  return __builtin_amdgcn_rcpf(1.0f + __builtin_amdgcn_exp2f(-1.4426950408889634f * x));
}
__device__ __forceinline__ float tanh_f(float x) {
  return 1.0f - 2.0f * __builtin_amdgcn_rcpf(1.0f + __builtin_amdgcn_exp2f(2.8853900817779268f * x));
}

// h fragment buffers (round-7-verified layout, double-buffered by t&1):
// chunk (kt, quadf, row) at byte kt*144 + quadf*32 + row*16 holds
// h_row[kt*32 + quadf*8 + j], j=0..7 (f16). b128 reads conflict-free.
#define FB_KT 144

#define MFMA16(a, b, c) __builtin_amdgcn_mfma_f32_16x16x32_f16((a), (b), (c), 0, 0, 0)

// 256 blocks x 1024 threads (16 waves), 2 batch rows/block.
// In-wave activation. Wave w owns hids [8w, 8w+8) of BOTH layers.
// A-operand row m (= lane&15 in the A fragment) = 4*(m>>2) + (m&3) holds
// gate e=m&3 of hid 8w + 2*(m>>2) + mt. With C-layout (col=lane&15,
// row=quad*4+reg, quad=lane>>4), lane (quad=Q, col=n) then holds the full
// (i,f,g,o) of hids 8w+2Q (acc0) and 8w+2Q+1 (acc1) for batch n&1:
// activation + c-update happen IN the MFMA wave. No gate LDS round-trip.
// ROUND-12 FIX (r11 bug): update-path hid index and h-write offset must use
// quad (=lane>>4, the C-layout M decode), NOT m15>>2 (the A-layout decode).
// r11 used m15>>2 (=0 in update lanes m15<2): wrong constants + all quads'
// h-writes colliding on one dword -> absmax 3.6e-2.
// Per step, 2 barriers:
//   phaseA: g1(t)=A1@h1(t-1) (8 MFMA) and car=A2h@h2(t-1) (8 MFMA)
//           -> +wx*x+b, activate -> c1,h1(t) -> hb1[p^1]; wave0 folds
//           outp partials of t-1 -> xlds park. barrier.
//   phaseB: g2(t)=A2i@h1(t)+car+b (8 MFMA) -> c2,h2(t) -> hb2[p^1];
//           out partial (2 shfls) -> outp. barrier.
__global__ __launch_bounds__(1024) void lstm_mfma(
    const float* __restrict__ x,
    const float* __restrict__ w_ih1,
    const float* __restrict__ w_hh1,
    const float* __restrict__ b_ih1,
    const float* __restrict__ b_hh1,
    const float* __restrict__ w_ih2,
    const float* __restrict__ w_hh2,
    const float* __restrict__ b_ih2,
    const float* __restrict__ b_hh2,
    const float* __restrict__ w_lin,
    const float* __restrict__ b_lin,
    float* __restrict__ out)
{
  __shared__ __align__(16) float xlds[2][L_];               // x rows; recycled as out
  __shared__ __align__(16) unsigned char hb1[2][4 * FB_KT]; // h1 frag, dbuf
  __shared__ __align__(16) unsigned char hb2[2][4 * FB_KT]; // h2 frag, dbuf
  __shared__ __align__(16) float outp[32];                  // per-wave out partials

  const int tid  = threadIdx.x;
  const int wv   = tid >> 6;
  const int lane = tid & 63;
  const int quad = lane >> 4;
  const int m15  = lane & 15;
  const int qa   = m15 >> 2;     // A-fragment row decode: row m15 = 4*qa+ea
  const int ea   = m15 & 3;
  const int nn   = m15 & 1;      // batch row for this lane's C column
  const int r0   = blockIdx.x * 2;
  const int Hs   = 8 * wv;       // this wave's hid slice

  // ---- one-time staging ----
  for (int i = tid; i < 2 * L_; i += 1024) ((float*)xlds)[i] = x[r0 * L_ + i];
  if (tid < FB_KT) {  // each buffer = 4*FB_KT bytes = FB_KT dwords
    ((unsigned*)hb1[0])[tid] = 0u; ((unsigned*)hb1[1])[tid] = 0u;
    ((unsigned*)hb2[0])[tid] = 0u; ((unsigned*)hb2[1])[tid] = 0u;
  }

  // ---- per-lane constants for its two hids: hidA = Hs+2*QUAD (C decode!) ----
  const int hidA = Hs + 2 * quad;
  float wxA[4], wxB[4], b1A[4], b1B[4], b2A[4], b2B[4];
#pragma unroll
  for (int g = 0; g < 4; ++g) {
    const int ra = g * H_ + hidA;      // gate g row of hidA
    wxA[g] = w_ih1[ra];       wxB[g] = w_ih1[ra + 1];
    b1A[g] = b_ih1[ra] + b_hh1[ra];
    b1B[g] = b_ih1[ra + 1] + b_hh1[ra + 1];
    b2A[g] = b_ih2[ra] + b_hh2[ra];
    b2B[g] = b_ih2[ra + 1] + b_hh2[ra + 1];
  }
  const float wlA = w_lin[hidA], wlB = w_lin[hidA + 1];
  const float blv = b_lin[0];

  // ---- A-fragments: A-row m15 = 4qa+ea -> gate ea of hid Hs+2qa+mt ----
  v8h A1[2][4], A2i[2][4], A2h[2][4];
#pragma unroll
  for (int mt = 0; mt < 2; ++mt) {
    const int grow = (ea * H_ + Hs + 2 * qa + mt) * H_;
#pragma unroll
    for (int kt = 0; kt < 4; ++kt) {
      const int koff = kt * 32 + quad * 8;
      float4 a, b;
      a = *(const float4*)(w_hh1 + grow + koff);
      b = *(const float4*)(w_hh1 + grow + koff + 4);
      A1[mt][kt] = v8h{(_Float16)a.x, (_Float16)a.y, (_Float16)a.z, (_Float16)a.w,
                       (_Float16)b.x, (_Float16)b.y, (_Float16)b.z, (_Float16)b.w};
      a = *(const float4*)(w_ih2 + grow + koff);
      b = *(const float4*)(w_ih2 + grow + koff + 4);
      A2i[mt][kt] = v8h{(_Float16)a.x, (_Float16)a.y, (_Float16)a.z, (_Float16)a.w,
                        (_Float16)b.x, (_Float16)b.y, (_Float16)b.z, (_Float16)b.w};
      a = *(const float4*)(w_hh2 + grow + koff);
      b = *(const float4*)(w_hh2 + grow + koff + 4);
      A2h[mt][kt] = v8h{(_Float16)a.x, (_Float16)a.y, (_Float16)a.z, (_Float16)a.w,
                        (_Float16)b.x, (_Float16)b.y, (_Float16)b.z, (_Float16)b.w};
    }
  }

  float c1a = 0.f, c1b = 0.f, c2a = 0.f, c2b = 0.f;  // per-lane cell state
  // b128 B-read offset (cols replicate batch rows: col n -> row n&1)
  const int hroff = quad * 32 + nn * 16;
  // h-write: hid pair Hs+2*quad -> chunk (wv>>2, wv&3), row nn, dword quad
  const int hwoff = (wv >> 2) * FB_KT + (wv & 3) * 32 + nn * 16 + 4 * quad;
  const bool upd  = (m15 < 2);

  __syncthreads();

  for (int t = 0; t <= L_; ++t) {
    const int p = t & 1;
    v4f car0 = {0.f, 0.f, 0.f, 0.f}, car1 = {0.f, 0.f, 0.f, 0.f};

    // ---- phaseA: layer-1 gates + layer-2 h2-carry; update c1/h1 ----
    if (t < L_) {
      v4f a0 = {0.f, 0.f, 0.f, 0.f}, a1 = {0.f, 0.f, 0.f, 0.f};
#pragma unroll
      for (int kt = 0; kt < 4; ++kt) {
        v8h bv1 = *(const v8h*)(hb1[p] + kt * FB_KT + hroff);
        v8h bv2 = *(const v8h*)(hb2[p] + kt * FB_KT + hroff);
        a0   = MFMA16(A1[0][kt],  bv1, a0);
        a1   = MFMA16(A1[1][kt],  bv1, a1);
        car0 = MFMA16(A2h[0][kt], bv2, car0);
        car1 = MFMA16(A2h[1][kt], bv2, car1);
      }
      const float xv = xlds[nn][t];
      float i0 = sigmoid_f(a0.x + wxA[0] * xv + b1A[0]);
      float f0 = sigmoid_f(a0.y + wxA[1] * xv + b1A[1]);
      float g0 = tanh_f  (a0.z + wxA[2] * xv + b1A[2]);
      float o0 = sigmoid_f(a0.w + wxA[3] * xv + b1A[3]);
      c1a = f0 * c1a + i0 * g0;
      float hA = o0 * tanh_f(c1a);
      float i1 = sigmoid_f(a1.x + wxB[0] * xv + b1B[0]);
      float f1 = sigmoid_f(a1.y + wxB[1] * xv + b1B[1]);
      float g1 = tanh_f  (a1.z + wxB[2] * xv + b1B[2]);
      float o1 = sigmoid_f(a1.w + wxB[3] * xv + b1B[3]);
      c1b = f1 * c1b + i1 * g1;
      float hB = o1 * tanh_f(c1b);
      if (upd)
        *(unsigned*)(hb1[p ^ 1] + hwoff) =
            __builtin_bit_cast(unsigned, h2t{(_Float16)hA, (_Float16)hB});
    }
    // wave 0: finish out(t-1) from phaseB(t-1) partials
    if (t > 0 && wv == 0) {
      float v = outp[lane & 31];
      v += __shfl_xor(v, 2);
      v += __shfl_xor(v, 4);
      v += __shfl_xor(v, 8);
      v += __shfl_xor(v, 16);
      if (lane < 2) xlds[lane][t - 1] = v + blv;
    }
    __syncthreads();

    // ---- phaseB: layer-2 gates; update c2/h2; out partial ----
    if (t < L_) {
      v4f a0 = car0, a1 = car1;
#pragma unroll
      for (int kt = 0; kt < 4; ++kt) {
        v8h bv1 = *(const v8h*)(hb1[p ^ 1] + kt * FB_KT + hroff);
        a0 = MFMA16(A2i[0][kt], bv1, a0);
        a1 = MFMA16(A2i[1][kt], bv1, a1);
      }
      float i0 = sigmoid_f(a0.x + b2A[0]);
      float f0 = sigmoid_f(a0.y + b2A[1]);
      float g0 = tanh_f  (a0.z + b2A[2]);
      float o0 = sigmoid_f(a0.w + b2A[3]);
      c2a = f0 * c2a + i0 * g0;
      float hA = o0 * tanh_f(c2a);
      float i1 = sigmoid_f(a1.x + b2B[0]);
      float f1 = sigmoid_f(a1.y + b2B[1]);
      float g1 = tanh_f  (a1.z + b2B[2]);
      float o1 = sigmoid_f(a1.w + b2B[3]);
      c2b = f1 * c2b + i1 * g1;
      float hB = o1 * tanh_f(c2b);
      if (upd)
        *(unsigned*)(hb2[p ^ 1] + hwoff) =
            __builtin_bit_cast(unsigned, h2t{(_Float16)hA, (_Float16)hB});
      float pp = upd ? (hA * wlA + hB * wlB) : 0.f;
      pp += __shfl_xor(pp, 16);   // sum over quads: lanes {n,16+n,32+n,48+n}
      pp += __shfl_xor(pp, 32);
      if (lane < 2) outp[wv * 2 + lane] = pp;
      __syncthreads();
    }
  }

  // ---- coalesced output flush ----
  for (int i = tid; i < 2 * L_; i += 1024) out[r0 * L_ + i] = ((float*)xlds)[i];
}

extern "C" void kernel_launch(void* const* d_in, const int* in_sizes, int n_in,
                              void* d_out, int out_size, void* d_ws, size_t ws_size,
                              hipStream_t stream) {
  const float* x     = (const float*)d_in[0];
  const float* w_ih1 = (const float*)d_in[1];
  const float* w_hh1 = (const float*)d_in[2];
  const float* b_ih1 = (const float*)d_in[3];
  const float* b_hh1 = (const float*)d_in[4];
  const float* w_ih2 = (const float*)d_in[5];
  const float* w_hh2 = (const float*)d_in[6];
  const float* b_ih2 = (const float*)d_in[7];
  const float* b_hh2 = (const float*)d_in[8];
  const float* w_lin = (const float*)d_in[9];
  const float* b_lin = (const float*)d_in[10];

  lstm_mfma<<<B_ / 2, 1024, 0, stream>>>(
      x, w_ih1, w_hh1, b_ih1, b_hh1, w_ih2, w_hh2, b_ih2, b_hh2,
      w_lin, b_lin, (float*)d_out);
}